// Round 5
// baseline (239.400 us; speedup 1.0000x reference)
//
#include <hip/hip_runtime.h>
#include <hip/hip_bf16.h>

#define NN 20000
#define CC 128

typedef __attribute__((ext_vector_type(8))) _Float16 half8;
typedef __attribute__((ext_vector_type(2))) _Float16 half2v;
typedef __attribute__((ext_vector_type(4))) float f32x4;

typedef const __attribute__((address_space(1))) void gv_t;
typedef __attribute__((address_space(3))) void sv_t;

#define TBL_SCALE 85.333336f  // 2048/24 == 1024/12

// ---------- one-shot conversions + gate LUT build ----------
__global__ __launch_bounds__(256) void conv_all_kernel(
    const float* __restrict__ Wf0, const float* __restrict__ Ws0,
    const float* __restrict__ Wf1, const float* __restrict__ Ws1,
    const float* __restrict__ Wf2, const float* __restrict__ Ws2,
    const float* __restrict__ Wf3, const float* __restrict__ Ws3,
    const float* __restrict__ We2, const float* __restrict__ We1,
    const float* __restrict__ xprot,
    _Float16* __restrict__ WctAll, _Float16* __restrict__ Wcte,
    _Float16* __restrict__ Wt1, _Float16* __restrict__ xp16,
    float* __restrict__ tbl) {
    int id = blockIdx.x * 256 + threadIdx.x;
    if (id < 262144) {
        int Lw = id >> 16;
        int i = id & 65535;
        int c = i & 511;
        int k = i >> 9;
        const float* Wfp = (Lw == 0) ? Wf0 : (Lw == 1) ? Wf1 : (Lw == 2) ? Wf2 : Wf3;
        const float* Wsp = (Lw == 0) ? Ws0 : (Lw == 1) ? Ws1 : (Lw == 2) ? Ws2 : Ws3;
        float v;
        if (c < 128) v = Wfp[k * 128 + c];
        else if (c < 256) v = Wfp[(128 + k) * 128 + (c - 128)];
        else if (c < 384) v = Wsp[k * 128 + (c - 256)];
        else v = Wsp[(128 + k) * 128 + (c - 384)];
        WctAll[Lw * 65536 + c * 128 + k] = (_Float16)v;
    } else if (id < 278528) {
        int i = id - 262144;
        int c = i & 127;
        int k = i >> 7;
        Wcte[c * 128 + k] = (_Float16)We2[k * 128 + c];
    } else if (id < 282624) {
        int i = id - 278528;
        int c = i & 127;
        int k = i >> 7;  // k < 32
        Wt1[c * 32 + k] = (_Float16)We1[k * 128 + c];
    } else if (id < 922624) {
        int i = id - 282624;  // < 640000
        xp16[i] = (_Float16)xprot[i];
    } else if (id < 924672) {
        // sigmoid table over f' in [-12,12), midpoint sampled (base-2 domain)
        int i = id - 922624;  // < 2048
        float fp = (i + 0.5f) * (24.0f / 2048.0f) - 12.0f;
        tbl[i] = 1.0f / (1.0f + exp2f(-fp));
    } else if (id < 925696) {
        // softplus correction c(t) = log2(1+2^-t), t in [0,12)
        int j = id - 924672;  // < 1024
        float tt = (j + 0.5f) * (12.0f / 1024.0f);
        tbl[2048 + j] = log2f(1.0f + exp2f(-tt));
    }
}

// ---------- encoder layer 1 via MFMA: (N x 32) @ (32 x 128) + b, relu -> f16 ----------
__global__ __launch_bounds__(256) void enc1_mfma_kernel(
    const _Float16* __restrict__ A, const _Float16* __restrict__ Wt1,
    const float* __restrict__ b, _Float16* __restrict__ Y) {
    int t = threadIdx.x;
    int wid = t >> 6, l = t & 63;
    int lr = l & 15, hi = l >> 4;
    int m0 = blockIdx.x * 128 + wid * 32;
    half8 af[2];
#pragma unroll
    for (int m = 0; m < 2; ++m) {
        int row = m0 + m * 16 + lr;
        half8 v = {0, 0, 0, 0, 0, 0, 0, 0};
        if (row < NN) v = *(const half8*)(A + (long)row * 32 + hi * 8);
        af[m] = v;
    }
    f32x4 acc[2][8] = {};
#pragma unroll
    for (int n = 0; n < 8; ++n) {
        int col = n * 16 + lr;
        half8 bg = *(const half8*)(Wt1 + (long)col * 32 + hi * 8);
#pragma unroll
        for (int m = 0; m < 2; ++m)
            acc[m][n] = __builtin_amdgcn_mfma_f32_16x16x32_f16(af[m], bg, acc[m][n], 0, 0, 0);
    }
#pragma unroll
    for (int n = 0; n < 8; ++n) {
        int col = n * 16 + lr;
        float bb = b[col];
#pragma unroll
        for (int m = 0; m < 2; ++m) {
#pragma unroll
            for (int q = 0; q < 4; ++q) {
                int row = m0 + m * 16 + hi * 4 + q;
                if (row < NN)
                    Y[(long)row * 128 + col] = (_Float16)fmaxf(acc[m][n][q] + bb, 0.0f);
            }
        }
    }
}

// ---------- MFMA GEMM: Y[M x ncol] = A[M x 128] @ W[128 x ncol] ----------
__global__ __launch_bounds__(256) void gemm_mfma_kernel(
    const _Float16* __restrict__ A, const _Float16* __restrict__ Wt,
    const float* __restrict__ bias0, const float* __restrict__ bias1,
    _Float16* __restrict__ outH, float* __restrict__ outF,
    _Float16* __restrict__ outF16, int M, int mode) {
    __shared__ _Float16 lds[32768];  // 64 KB
    int t = threadIdx.x;
    int w = t >> 6, l = t & 63;
    int m0 = blockIdx.x * 128;
    int n0 = blockIdx.y * 128;
    {
        int rin = l >> 4;
        int cs = l & 15;
#pragma unroll
        for (int j = 0; j < 8; ++j) {
            int r = w * 32 + j * 4 + rin;
            int g = cs ^ (r & 7);
            int grow = m0 + r;
            if (grow > M - 1) grow = M - 1;
            const _Float16* srcA = A + (long)grow * 128 + g * 8;
            __builtin_amdgcn_global_load_lds((gv_t*)srcA,
                (sv_t*)&lds[(w * 32 + j * 4) * 128], 16, 0, 0);
            const _Float16* srcB = Wt + (long)(n0 + r) * 128 + g * 8;
            __builtin_amdgcn_global_load_lds((gv_t*)srcB,
                (sv_t*)&lds[16384 + (w * 32 + j * 4) * 128], 16, 0, 0);
        }
    }
    __syncthreads();
    int wm = w >> 1, wn = w & 1;
    int lr = l & 15, hi = l >> 4;
    f32x4 acc[4][4] = {};
#pragma unroll
    for (int ks = 0; ks < 4; ++ks) {
        int cidx = 4 * ks + hi;
        half8 af[4], bg[4];
#pragma unroll
        for (int m = 0; m < 4; ++m) {
            int row = wm * 64 + m * 16 + lr;
            af[m] = *(const half8*)(&lds[row * 128 + (cidx ^ (row & 7)) * 8]);
        }
#pragma unroll
        for (int n = 0; n < 4; ++n) {
            int row = wn * 64 + n * 16 + lr;
            bg[n] = *(const half8*)(&lds[16384 + row * 128 + (cidx ^ (row & 7)) * 8]);
        }
#pragma unroll
        for (int m = 0; m < 4; ++m)
#pragma unroll
            for (int n = 0; n < 4; ++n)
                acc[m][n] = __builtin_amdgcn_mfma_f32_16x16x32_f16(
                    af[m], bg[n], acc[m][n], 0, 0, 0);
    }
    if (mode == 0) {
        __syncthreads();
        const float S = 1.44269504f;
#pragma unroll
        for (int n = 0; n < 4; ++n) {
            int cl = wn * 64 + n * 16 + lr;
            int gcol = n0 + cl;
            float badd = (gcol < 128) ? bias0[gcol]
                       : ((gcol >= 256 && gcol < 384) ? bias1[gcol - 256] : 0.0f);
#pragma unroll
            for (int m = 0; m < 4; ++m)
#pragma unroll
                for (int q = 0; q < 4; ++q) {
                    int rl = wm * 64 + m * 16 + hi * 4 + q;
                    lds[rl * 144 + cl] = (_Float16)((acc[m][n][q] + badd) * S);
                }
        }
        __syncthreads();
#pragma unroll
        for (int i = 0; i < 8; ++i) {
            int id = t + 256 * i;
            int row = id >> 4, ch = id & 15;
            int grow = m0 + row;
            if (grow < M) {
                half8 v = *(const half8*)(&lds[row * 144 + ch * 8]);
                *(half8*)(&outH[(long)grow * 512 + n0 + ch * 8]) = v;
            }
        }
    } else {
#pragma unroll
        for (int n = 0; n < 4; ++n) {
            int gcol = n0 + wn * 64 + n * 16 + lr;
            float badd = bias0[gcol];
#pragma unroll
            for (int m = 0; m < 4; ++m)
#pragma unroll
                for (int q = 0; q < 4; ++q) {
                    int grow = m0 + wm * 64 + m * 16 + hi * 4 + q;
                    if (grow < M) {
                        float v = acc[m][n][q] + badd;
                        outF[(long)grow * 128 + gcol] = v;
                        outF16[(long)grow * 128 + gcol] = (_Float16)v;
                    }
                }
        }
    }
}

// ---------- bond CSR build ----------
__global__ __launch_bounds__(256) void count_int_kernel(
    const int* __restrict__ dst, int E, int* __restrict__ cnt) {
    int e = blockIdx.x * 256 + threadIdx.x;
    if (e < E) atomicAdd(&cnt[dst[e]], 1);
}

__global__ __launch_bounds__(1024) void scan_kernel(
    const int* __restrict__ cnt, int* __restrict__ off) {
    __shared__ int part[1024];
    int t = threadIdx.x;
    int base = t * 20;
    int loc[20];
    int s = 0;
#pragma unroll
    for (int i = 0; i < 20; ++i) {
        int idx = base + i;
        int v = (idx < NN) ? cnt[idx] : 0;
        loc[i] = s;
        s += v;
    }
    part[t] = s;
    __syncthreads();
    for (int d = 1; d < 1024; d <<= 1) {
        int v = (t >= d) ? part[t - d] : 0;
        __syncthreads();
        part[t] += v;
        __syncthreads();
    }
    int pre = (t > 0) ? part[t - 1] : 0;
#pragma unroll
    for (int i = 0; i < 20; ++i) {
        int idx = base + i;
        if (idx < NN) off[idx] = pre + loc[i];
    }
    if (t == 1023) off[NN] = part[1023];
}

__global__ __launch_bounds__(256) void scatter_kernel(
    const int* __restrict__ src, const int* __restrict__ dst, int E,
    const int* __restrict__ off, int* __restrict__ cur, int* __restrict__ eid) {
    int e = blockIdx.x * 256 + threadIdx.x;
    if (e < E) {
        int d = dst[e];
        int p = off[d] + atomicAdd(&cur[d], 1);
        eid[p] = src[e];
    }
}

// ---------- radius CSR offsets via binary search (dst sorted) ----------
__global__ __launch_bounds__(256) void csr_off_kernel(
    const int* __restrict__ dst, int E, int N1, int* __restrict__ off) {
    int n = blockIdx.x * 256 + threadIdx.x;
    if (n >= N1) return;
    int lo = 0, hi = E;
    while (lo < hi) {
        int mid = (lo + hi) >> 1;
        if (dst[mid] < n) lo = mid + 1;
        else hi = mid;
    }
    off[n] = lo;
}

// ---------- unified node-centric aggregation, LUT gate, persistent grid ----------
// H pre-scaled by log2(e). sig via sigT[2048] over [-12,12);
// softplus = ln2*(max(s',0) + cT[|s'|]), cT[1024] over [0,12). ln2 folded into inv.
__global__ __launch_bounds__(256) void node_agg_kernel(
    const _Float16* __restrict__ H, const int* __restrict__ srcArr,
    const int* __restrict__ off, const float* __restrict__ xin,
    float* __restrict__ xout, _Float16* __restrict__ xh,
    const float* __restrict__ tblG, int write_h) {
    __shared__ float sigT[2048];
    __shared__ float cT[1024];
    int t = threadIdx.x;
    for (int i = t; i < 3072; i += 256) {
        float v = tblG[i];
        if (i < 2048) sigT[i] = v;
        else cT[i - 2048] = v;
    }
    __syncthreads();
    int l = t & 63;
    int wn = t >> 6;
    const half2v* H2 = (const half2v*)H;
    for (int n = blockIdx.x * 4 + wn; n < NN; n += gridDim.x * 4) {
        int nu = __builtin_amdgcn_readfirstlane(n);
        const half2v* hrow = H2 + (long)nu * 256;
        half2v fdh = hrow[l];
        half2v sdh = hrow[128 + l];
        int e0 = __builtin_amdgcn_readfirstlane(off[nu]);
        int e1 = __builtin_amdgcn_readfirstlane(off[nu + 1]);
        float ax = 0.0f, ay = 0.0f;
#define EDGEC(fv, sv)                                                      \
    {                                                                      \
        half2v fsum = fdh + (fv);                                          \
        half2v ssum = sdh + (sv);                                          \
        float fx = (float)fsum.x, fy = (float)fsum.y;                      \
        float sx = (float)ssum.x, sy = (float)ssum.y;                      \
        float tfx = fminf(fmaxf(__builtin_fmaf(fx, TBL_SCALE, 1024.0f), 0.0f), 2047.0f); \
        float tfy = fminf(fmaxf(__builtin_fmaf(fy, TBL_SCALE, 1024.0f), 0.0f), 2047.0f); \
        float tsx = fminf(fabsf(sx) * TBL_SCALE, 1023.0f);                 \
        float tsy = fminf(fabsf(sy) * TBL_SCALE, 1023.0f);                 \
        float gx = sigT[(int)tfx];                                         \
        float gy = sigT[(int)tfy];                                         \
        float spx = fmaxf(sx, 0.0f) + cT[(int)tsx];                        \
        float spy = fmaxf(sy, 0.0f) + cT[(int)tsy];                        \
        ax += gx * spx;                                                    \
        ay += gy * spy;                                                    \
    }
        int e = e0;
        for (; e + 3 < e1; e += 4) {
            int s0 = srcArr[e], s1 = srcArr[e + 1];
            int s2 = srcArr[e + 2], s3 = srcArr[e + 3];
            const half2v* h0 = H2 + (long)s0 * 256;
            const half2v* h1 = H2 + (long)s1 * 256;
            const half2v* h2 = H2 + (long)s2 * 256;
            const half2v* h3 = H2 + (long)s3 * 256;
            half2v f0 = h0[64 + l], g0 = h0[192 + l];
            half2v f1 = h1[64 + l], g1 = h1[192 + l];
            half2v f2 = h2[64 + l], g2 = h2[192 + l];
            half2v f3 = h3[64 + l], g3 = h3[192 + l];
            EDGEC(f0, g0) EDGEC(f1, g1) EDGEC(f2, g2) EDGEC(f3, g3)
        }
        for (; e < e1; ++e) {
            int s0 = srcArr[e];
            const half2v* h0 = H2 + (long)s0 * 256;
            half2v f0 = h0[64 + l], g0 = h0[192 + l];
            EDGEC(f0, g0)
        }
#undef EDGEC
        float inv = 0.6931471805599453f *
                    __builtin_amdgcn_rcpf(fmaxf((float)(e1 - e0), 1.0f));
        float2 xv = ((const float2*)xin)[(long)nu * 64 + l];
        float ox = fmaxf(xv.x + ax * inv, 0.0f);
        float oy = fmaxf(xv.y + ay * inv, 0.0f);
        ((float2*)xout)[(long)nu * 64 + l] = make_float2(ox, oy);
        if (write_h) {
            half2v oh;
            oh.x = (_Float16)ox;
            oh.y = (_Float16)oy;
            ((half2v*)xh)[(long)nu * 64 + l] = oh;
        }
    }
}

extern "C" void kernel_launch(void* const* d_in, const int* in_sizes, int n_in,
                              void* d_out, int out_size, void* d_ws, size_t ws_size,
                              hipStream_t stream) {
    const float* x_prot = (const float*)d_in[0];
    const int* eb = (const int*)d_in[2];
    const int* er = (const int*)d_in[3];
    int Eb = in_sizes[2] / 2;
    int Er = in_sizes[3] / 2;
    const float* We1 = (const float*)d_in[4];
    const float* be1 = (const float*)d_in[5];
    const float* We2 = (const float*)d_in[6];
    const float* be2 = (const float*)d_in[7];
    const float* Wf[4]  = {(const float*)d_in[8],  (const float*)d_in[12],
                           (const float*)d_in[16], (const float*)d_in[20]};
    const float* bf[4]  = {(const float*)d_in[9],  (const float*)d_in[13],
                           (const float*)d_in[17], (const float*)d_in[21]};
    const float* Wsp[4] = {(const float*)d_in[10], (const float*)d_in[14],
                           (const float*)d_in[18], (const float*)d_in[22]};
    const float* bsp[4] = {(const float*)d_in[11], (const float*)d_in[15],
                           (const float*)d_in[19], (const float*)d_in[23]};

    char* ws = (char*)d_ws;
    float*     xbuf  = (float*)ws;                        // 10,240,000
    _Float16*  xhf   = (_Float16*)(ws + 10240000);        //  5,120,000
    _Float16*  H     = (_Float16*)(ws + 15360000);        // 20,480,000
    _Float16*  xp16  = (_Float16*)(ws + 35840000);        //  1,280,000
    int*       cntI  = (int*)(ws + 37120000);             //     80,000
    int*       curB  = (int*)(ws + 37200000);             //     80,000
    int*       offB  = (int*)(ws + 37280000);             //     80,016
    int*       offR  = (int*)(ws + 37360016);             //     80,016
    int*       eidB  = (int*)(ws + 37440032);             //    320,000
    _Float16*  WctAll= (_Float16*)(ws + 37760032);        //    524,288
    _Float16*  Wcte  = (_Float16*)(ws + 38284320);        //     32,768
    _Float16*  Wt1   = (_Float16*)(ws + 38317088);        //      8,192
    float*     tbl   = (float*)(ws + 38325280);           //     12,288

    const int* srcB = eb;
    const int* dstB = eb + Eb;
    const int* srcR = er;

    // conversions + LUT build (one kernel)
    conv_all_kernel<<<3616, 256, 0, stream>>>(
        Wf[0], Wsp[0], Wf[1], Wsp[1], Wf[2], Wsp[2], Wf[3], Wsp[3],
        We2, We1, x_prot, WctAll, Wcte, Wt1, xp16, tbl);

    // bond CSR build + radius CSR offsets
    hipMemsetAsync(cntI, 0, 160000, stream);  // cntI + curB contiguous
    count_int_kernel<<<(Eb + 255) / 256, 256, 0, stream>>>(dstB, Eb, cntI);
    scan_kernel<<<1, 1024, 0, stream>>>(cntI, offB);
    scatter_kernel<<<(Eb + 255) / 256, 256, 0, stream>>>(srcB, dstB, Eb, offB, curB, eidB);
    csr_off_kernel<<<(NN + 256) / 256, 256, 0, stream>>>(er + Er, Er, NN + 1, offR);

    // encoder
    enc1_mfma_kernel<<<157, 256, 0, stream>>>(xp16, Wt1, be1, H);
    {
        dim3 g(157, 1);
        gemm_mfma_kernel<<<g, 256, 0, stream>>>(H, Wcte, be2, be2, nullptr,
                                                xbuf, xhf, NN, 1);
    }

    // 4 CGConv layers (0-1: bond CSR, 2-3: radius CSR)
    for (int L = 0; L < 4; ++L) {
        dim3 g(157, 4);
        gemm_mfma_kernel<<<g, 256, 0, stream>>>(xhf, WctAll + L * 65536, bf[L],
                                                bsp[L], H, nullptr, nullptr, NN, 0);
        const int* sArr = (L < 2) ? eidB : srcR;
        const int* oArr = (L < 2) ? offB : offR;
        float* xout = (L == 3) ? (float*)d_out : xbuf;
        node_agg_kernel<<<2048, 256, 0, stream>>>(H, sArr, oArr, xbuf, xout,
                                                  xhf, tbl, (L == 3) ? 0 : 1);
    }
    (void)n_in; (void)out_size; (void)ws_size;
}